// Round 1
// baseline (252.893 us; speedup 1.0000x reference)
//
#include <hip/hip_runtime.h>
#include <math.h>

// Shapes (fixed by the reference): B=2, N=32, L=4, ED=64, H=4, HD=16
#define B 2
#define N 32
#define L 4
#define ED 64
#define H 4
#define HD 16
#define EPS 1e-5f
#define ROWS (B * N * N)  // 2048

// ---------------------------------------------------------------------------
// K0: build dense adjacency. Single block so the diag overwrite is ordered
// after all edge atomicAdds.
__global__ void k_adj(const int* __restrict__ ei, const int* __restrict__ batch,
                      float* __restrict__ adj, int E) {
    int t = threadIdx.x;
    for (int i = t; i < B * N * N; i += blockDim.x) adj[i] = 0.0f;
    __syncthreads();
    for (int e = t; e < E; e += blockDim.x) {
        int e0 = ei[e];
        int e1 = ei[E + e];
        int g  = batch[e0];
        int ls = e0 - g * N;
        int ld = e1 - g * N;
        atomicAdd(&adj[(g * N + ls) * N + ld], 1.0f);
    }
    __syncthreads();
    if (t < B * N) {
        int b = t / N, n = t % N;
        adj[(b * N + n) * N + n] = 2.0f;
    }
}

// ---------------------------------------------------------------------------
// K1: h = x @ W.T + b ; q = per-head LayerNorm(h) (mean/var over HD=16).
// One thread per output channel; 4 rows per 256-thread block.
__global__ void k_lin_ln(const float* __restrict__ x, const float* __restrict__ W,
                         const float* __restrict__ b, const float* __restrict__ lg,
                         const float* __restrict__ lb, float* __restrict__ h,
                         float* __restrict__ q, int Cin) {
    int rl  = threadIdx.x / 64;
    int c   = threadIdx.x % 64;
    int row = blockIdx.x * 4 + rl;

    __shared__ float xs[4][64];
    if (c < Cin) xs[rl][c] = x[row * Cin + c];
    __syncthreads();

    const float* xr = xs[rl];
    const float* Wr = W + c * Cin;
    float acc = b[c];
    for (int j = 0; j < Cin; ++j) acc += Wr[j] * xr[j];
    h[row * 64 + c] = acc;

    // LN across the 16 channels of this head (16 consecutive lanes)
    float s = acc;
    for (int m = 1; m < 16; m <<= 1) s += __shfl_xor(s, m, 16);
    float mean = s * (1.0f / 16.0f);
    float dv = acc - mean;
    float s2 = dv * dv;
    for (int m = 1; m < 16; m <<= 1) s2 += __shfl_xor(s2, m, 16);
    float var = s2 * (1.0f / 16.0f);
    int d = c % 16;
    q[row * 64 + c] = dv * rsqrtf(var + EPS) * lg[d] + lb[d];
}

// ---------------------------------------------------------------------------
// K2: fused attention. One thread per (b,x,y,head,d). Online softmax over a,
// product-LN fused inline. 16-lane shuffle reductions (lanes of one head).
__global__ void k_attn(const float* __restrict__ h, const float* __restrict__ q,
                       const float* __restrict__ lg, const float* __restrict__ lb,
                       float* __restrict__ xu) {
    int t = blockIdx.x * blockDim.x + threadIdx.x;  // 0 .. 131071
    int c = t % 64;        // head*16 + d
    int d = c % 16;
    int r = t / 64;        // (b*32 + x)*32 + y
    int y = r % 32;
    int bx = r / 32;       // b*32 + x
    int b = bx / 32, x = bx % 32;

    float gl = lg[d], bl = lb[d];
    int base_x = ((b * 32 + x) * 32) * 64 + c;   // + a*64
    int base_y = ((b * 32) * 32 + y) * 64 + c;   // + a*2048

    float m = -1e30f, l = 0.0f, acc = 0.0f;
    for (int a = 0; a < 32; ++a) {
        float qx = q[base_x + a * 64];
        float qy = q[base_y + a * 2048];
        float sp = qx * qy;
        for (int mm = 1; mm < 16; mm <<= 1) sp += __shfl_xor(sp, mm, 16);
        float s = sp * 0.25f;   // / sqrt(HD)

        float hx = h[base_x + a * 64];
        float hy = h[base_y + a * 2048];
        float p = hx * hy;
        float ps = p;
        for (int mm = 1; mm < 16; mm <<= 1) ps += __shfl_xor(ps, mm, 16);
        float mean = ps * (1.0f / 16.0f);
        float dv = p - mean;
        float v2 = dv * dv;
        for (int mm = 1; mm < 16; mm <<= 1) v2 += __shfl_xor(v2, mm, 16);
        float n = dv * rsqrtf(v2 * (1.0f / 16.0f) + EPS) * gl;

        float nm = fmaxf(m, s);
        float sc = __expf(m - nm);
        float e  = __expf(s - nm);
        l   = l * sc + e;
        acc = acc * sc + e * n;
        m = nm;
    }
    xu[t] = acc / l + bl;   // softmax weights sum to 1 -> LN bias added once
}

// ---------------------------------------------------------------------------
// K3: y = concat([x, xu]) @ fW.T + fb, then LN over all 64 channels.
// In-place safe on x (each row reads only itself, staged through LDS).
__global__ void k_fin(const float* __restrict__ x, const float* __restrict__ xu,
                      const float* __restrict__ fW, const float* __restrict__ fb,
                      const float* __restrict__ fg, const float* __restrict__ fbeta,
                      float* __restrict__ xn, int Cin) {
    int rl  = threadIdx.x / 64;
    int c   = threadIdx.x % 64;
    int row = blockIdx.x * 4 + rl;

    __shared__ float cat[4][192];
    if (c < Cin) cat[rl][c] = x[row * Cin + c];
    cat[rl][Cin + c] = xu[row * 64 + c];
    __syncthreads();

    int K = Cin + 64;
    const float* Wr = fW + c * K;
    const float* cr = cat[rl];
    float acc = fb[c];
    for (int j = 0; j < K; ++j) acc += Wr[j] * cr[j];

    // full-wave LN over 64 channels
    float s = acc;
    for (int mm = 1; mm < 64; mm <<= 1) s += __shfl_xor(s, mm, 64);
    float mean = s * (1.0f / 64.0f);
    float dv = acc - mean;
    float s2 = dv * dv;
    for (int mm = 1; mm < 64; mm <<= 1) s2 += __shfl_xor(s2, mm, 64);
    float out = dv * rsqrtf(s2 * (1.0f / 64.0f) + EPS) * fg[c] + fbeta[c];
    xn[row * 64 + c] = out;
}

// ---------------------------------------------------------------------------
// K4: pooling partials per (b, n, e): min over m, max over off-diag m, diag.
__global__ void k_pool1(const float* __restrict__ x, float* __restrict__ pmin,
                        float* __restrict__ poff, float* __restrict__ pdiag) {
    int bn = blockIdx.x;      // b*32 + n
    int e  = threadIdx.x;     // 0..63
    int n  = bn % 32;
    const float* xp = x + bn * 32 * 64 + e;
    float mn = 1e30f, off = -1e30f, dg = 0.0f;
    for (int m2 = 0; m2 < 32; ++m2) {
        float v = xp[m2 * 64];
        mn = fminf(mn, v);
        if (m2 == n) dg = v;
        else off = fmaxf(off, v);
    }
    pmin[bn * 64 + e]  = mn;
    poff[bn * 64 + e]  = off;
    pdiag[bn * 64 + e] = dg;
}

// K5: finish pooling (global val, max_offdiag), then scores += pooled @ opW.T + opb
__global__ void k_pool2(const float* __restrict__ pmin, const float* __restrict__ poff,
                        const float* __restrict__ pdiag, const float* __restrict__ opW,
                        const float* __restrict__ opb, float* __restrict__ scores,
                        int first) {
    int t = threadIdx.x;      // 128 threads: (b, e)
    int b = t / 64, e = t % 64;
    float mn = 1e30f, off = -1e30f, dg = -1e30f;
    for (int n = 0; n < 32; ++n) {
        int idx = (b * 32 + n) * 64 + e;
        mn  = fminf(mn, pmin[idx]);
        off = fmaxf(off, poff[idx]);
        dg  = fmaxf(dg, pdiag[idx]);
    }
    __shared__ float smx[128], smn[128], pooled[2][128];
    smx[t] = dg;
    smn[t] = mn;
    __syncthreads();
    for (int s = 64; s > 0; s >>= 1) {
        if (t < s) {
            smx[t] = fmaxf(smx[t], smx[t + s]);
            smn[t] = fminf(smn[t], smn[t + s]);
        }
        __syncthreads();
    }
    float val = fabsf(smx[0] - smn[0]);  // |max_diag_global + max(-x)|
    pooled[b][e]      = dg;
    pooled[b][64 + e] = fmaxf(off, dg - val);
    __syncthreads();
    if (t < 64) {
        int bb = t / 32, c = t % 32;
        const float* Wr = opW + c * 128;
        float acc = opb[c];
        for (int j = 0; j < 128; ++j) acc += Wr[j] * pooled[bb][j];
        if (first) scores[t] = acc;
        else       scores[t] += acc;
    }
}

// ---------------------------------------------------------------------------
// K6: BatchNorm over the batch axis (B=2), biased variance.
__global__ void k_bn(const float* __restrict__ scores, float* __restrict__ out) {
    int c = threadIdx.x;  // 0..31
    float s0 = scores[c], s1 = scores[32 + c];
    float m = 0.5f * (s0 + s1);
    float v = 0.5f * ((s0 - m) * (s0 - m) + (s1 - m) * (s1 - m));
    float inv = rsqrtf(v + EPS);
    out[c]      = (s0 - m) * inv;
    out[32 + c] = (s1 - m) * inv;
}

// ---------------------------------------------------------------------------
extern "C" void kernel_launch(void* const* d_in, const int* in_sizes, int n_in,
                              void* d_out, int out_size, void* d_ws, size_t ws_size,
                              hipStream_t stream) {
    const int*   edge_index = (const int*)d_in[0];
    const int*   batch      = (const int*)d_in[1];
    const float* W0    = (const float*)d_in[2];
    const float* b0    = (const float*)d_in[3];
    const float* Ws    = (const float*)d_in[4];
    const float* bs    = (const float*)d_in[5];
    const float* ln_g  = (const float*)d_in[6];
    const float* ln_b  = (const float*)d_in[7];
    const float* fW0   = (const float*)d_in[8];
    const float* fb0   = (const float*)d_in[9];
    const float* fWs   = (const float*)d_in[10];
    const float* fbs   = (const float*)d_in[11];
    const float* fln_g = (const float*)d_in[12];
    const float* fln_b = (const float*)d_in[13];
    const float* opW   = (const float*)d_in[14];
    const float* opb   = (const float*)d_in[15];
    int E = in_sizes[0] / 2;

    float* ws     = (float*)d_ws;
    float* adj    = ws;                 // 2048
    float* x      = adj + 2048;         // 131072
    float* h      = x + ROWS * 64;      // 131072
    float* q      = h + ROWS * 64;      // 131072
    float* xu     = q + ROWS * 64;      // 131072
    float* pmin   = xu + ROWS * 64;     // 4096
    float* poff   = pmin + 4096;        // 4096
    float* pdiag  = poff + 4096;        // 4096
    float* scores = pdiag + 4096;       // 64

    k_adj<<<1, 1024, 0, stream>>>(edge_index, batch, adj, E);

    for (int i = 0; i < L; ++i) {
        const float* W  = (i == 0) ? W0  : Ws  + (i - 1) * 64 * 64;
        const float* b  = (i == 0) ? b0  : bs  + (i - 1) * 64;
        const float* fW = (i == 0) ? fW0 : fWs + (i - 1) * 64 * 128;
        const float* fb = (i == 0) ? fb0 : fbs + (i - 1) * 64;
        int Cin = (i == 0) ? 1 : 64;
        const float* xin = (i == 0) ? adj : x;

        k_lin_ln<<<ROWS / 4, 256, 0, stream>>>(xin, W, b, ln_g + i * HD,
                                               ln_b + i * HD, h, q, Cin);
        k_attn<<<ROWS * 64 / 256, 256, 0, stream>>>(h, q, ln_g + i * HD,
                                                    ln_b + i * HD, xu);
        k_fin<<<ROWS / 4, 256, 0, stream>>>(xin, xu, fW, fb, fln_g + i * 64,
                                            fln_b + i * 64, x, Cin);
        k_pool1<<<B * N, 64, 0, stream>>>(x, pmin, poff, pdiag);
        k_pool2<<<1, 128, 0, stream>>>(pmin, poff, pdiag, opW + i * 32 * 128,
                                       opb + i * 32, scores, (i == 0) ? 1 : 0);
    }

    k_bn<<<1, 32, 0, stream>>>(scores, (float*)d_out);
}